// Round 9
// baseline (70.525 us; speedup 1.0000x reference)
//
#include <hip/hip_runtime.h>

typedef __attribute__((ext_vector_type(8))) _Float16 f16x8;
typedef __attribute__((ext_vector_type(4))) _Float16 f16x4;
typedef __attribute__((ext_vector_type(4))) float   f32x4;

#define BATCH 16384
#define NFEAT 512
#define NCLS  1000
#define NLEAF 256
#define NINT  255
#define LDP   72    // staging LDS row stride (f16), 144B: 16B-aligned, 2-way banks
#define PSTR  257   // P LDS row stride (f32), odd: 2-way max on sigmoid writes
#define CSTR  260   // C LDS row stride (f32): mult-of-4 (16B align), mod32=4 -> 2-way max

// ---- convert gate_w (255x512) -> f16 padded to 256x512 (row 255 = 0) ----
__global__ __launch_bounds__(256) void cvt_gw(const float4* __restrict__ in,
                                              f16x4* __restrict__ out) {
  int i = blockIdx.x * 256 + threadIdx.x;
  int row = i >> 7;
  f16x4 o;
  if (row < NINT) {
    float4 v = in[i];
    o[0] = (_Float16)v.x; o[1] = (_Float16)v.y;
    o[2] = (_Float16)v.z; o[3] = (_Float16)v.w;
  } else {
    o[0] = o[1] = o[2] = o[3] = (_Float16)0.f;
  }
  out[i] = o;
}

// ---- softmax of leaf_logits rows -> distF in MFMA-fragment-swizzled layout ----
// (class c, leaf l) at ((c>>4)*8 + (l>>5))*512 + ((l>>3&3)*16 + (c&15))*8 + (l&7)
__global__ __launch_bounds__(256) void softmax_t(const float* __restrict__ L,
                                                 _Float16* __restrict__ distF) {
  __shared__ float red[4];
  const int l = blockIdx.x, t = threadIdx.x;
  const int wave = t >> 6, lane = t & 63;
  const int kt = l >> 5, lhi_l = (l >> 3) & 3, jj = l & 7;
  float v[4];
  const bool live = t < 250;
  if (live) {
    float4 f = *(const float4*)&L[(size_t)l * NCLS + t * 4];
    v[0] = f.x; v[1] = f.y; v[2] = f.z; v[3] = f.w;
  } else {
    v[0] = v[1] = v[2] = v[3] = -1e30f;
  }
  float mx = fmaxf(fmaxf(v[0], v[1]), fmaxf(v[2], v[3]));
#pragma unroll
  for (int s = 32; s; s >>= 1) mx = fmaxf(mx, __shfl_xor(mx, s));
  if (lane == 0) red[wave] = mx;
  __syncthreads();
  mx = fmaxf(fmaxf(red[0], red[1]), fmaxf(red[2], red[3]));
  __syncthreads();
  float e[4], sum = 0.f;
#pragma unroll
  for (int i = 0; i < 4; ++i) { e[i] = __expf(v[i] - mx); sum += e[i]; }
  if (!live) { e[0] = e[1] = e[2] = e[3] = 0.f; sum = 0.f; }
#pragma unroll
  for (int s = 32; s; s >>= 1) sum += __shfl_xor(sum, s);
  if (lane == 0) red[wave] = sum;
  __syncthreads();
  sum = red[0] + red[1] + red[2] + red[3];
  float inv = 1.f / sum;
#pragma unroll
  for (int i = 0; i < 4; ++i) {
    int c = t * 4 + i;
    float val = live ? e[i] * inv : 0.f;
    int c16 = c >> 4, ln = c & 15;
    size_t idx = (((size_t)(c16 * 8 + kt)) * 64 + lhi_l * 16 + ln) * 8 + jj;
    distF[idx] = (_Float16)val;
  }
}

// ---- fused: gemm1 + sigmoid + tree + gemm2 + row-streaming epilogue ----
// BM=64, 256 blocks (1/CU), 512 threads (8 waves). No launch-bounds cap (spills!).
__global__ __launch_bounds__(512)
void fused(const float* __restrict__ x, const _Float16* __restrict__ gwh,
           const float* __restrict__ gb, const _Float16* __restrict__ distF,
           float* __restrict__ out) {
  __shared__ union {
    struct { _Float16 A[64 * LDP]; _Float16 B[256 * LDP]; } s;  // 46,080 B
    float PC[64 * CSTR];                                        // 66,560 B (P: stride 257, C: 260)
  } sm;
  __shared__ _Float16 muF[32 * 512];                            // 32,768 B, fragment layout

  const int tid  = threadIdx.x;
  const int wave = tid >> 6, lane = tid & 63;
  const int ln15 = lane & 15, lhi = lane >> 4;
  const int wr = wave >> 2, wc = wave & 3;      // phase1: 2x4 waves, 32r x 64c
  const int r0 = blockIdx.x * 64;

  float bias_[4];
#pragma unroll
  for (int n = 0; n < 4; ++n) {
    int col = wc * 64 + n * 16 + ln15;
    bias_[n] = (col < NINT) ? gb[col] : 0.f;
  }

  // ---------------- phase 1: logits = x @ gwh^T (2-deep reg prefetch) ----------------
  f32x4 acc1[2][4] = {};
  const int arow = tid >> 4, acol = (tid & 15) * 4;
  const int brow = tid >> 3, bcol = (tid & 7) * 8;

  float4 pa_[2], pa2_[2];
  uint4  pb_[2][4];

#define P1_LOAD(s, k0)                                                           \
  {                                                                              \
    pa_[s]  = *(const float4*)&x[(size_t)(r0 + arow) * NFEAT + (k0) + acol];     \
    pa2_[s] = *(const float4*)&x[(size_t)(r0 + 32 + arow) * NFEAT + (k0) + acol];\
    _Pragma("unroll")                                                            \
    for (int i = 0; i < 4; ++i)                                                  \
      pb_[s][i] = *(const uint4*)&gwh[(size_t)(i * 64 + brow) * NFEAT + (k0) + bcol];\
  }
#define P1_WRITE(s)                                                              \
  {                                                                              \
    f16x4 h;                                                                     \
    h[0] = (_Float16)pa_[s].x; h[1] = (_Float16)pa_[s].y;                        \
    h[2] = (_Float16)pa_[s].z; h[3] = (_Float16)pa_[s].w;                        \
    *(f16x4*)&sm.s.A[arow * LDP + acol] = h;                                     \
    h[0] = (_Float16)pa2_[s].x; h[1] = (_Float16)pa2_[s].y;                      \
    h[2] = (_Float16)pa2_[s].z; h[3] = (_Float16)pa2_[s].w;                      \
    *(f16x4*)&sm.s.A[(32 + arow) * LDP + acol] = h;                              \
    _Pragma("unroll")                                                            \
    for (int i = 0; i < 4; ++i)                                                  \
      *(uint4*)&sm.s.B[(i * 64 + brow) * LDP + bcol] = pb_[s][i];                \
  }

  P1_LOAD(0, 0);
  P1_LOAD(1, 64);
#pragma unroll
  for (int k = 0; k < NFEAT / 64; ++k) {
    const int s = k & 1;
    P1_WRITE(s);
    __syncthreads();
    if (k + 2 < NFEAT / 64) P1_LOAD(s, (k + 2) * 64);
#pragma unroll
    for (int kk = 0; kk < 2; ++kk) {
      f16x8 a[2], b[4];
#pragma unroll
      for (int m = 0; m < 2; ++m)
        a[m] = *(const f16x8*)&sm.s.A[(wr * 32 + m * 16 + ln15) * LDP + kk * 32 + lhi * 8];
#pragma unroll
      for (int n = 0; n < 4; ++n)
        b[n] = *(const f16x8*)&sm.s.B[(wc * 64 + n * 16 + ln15) * LDP + kk * 32 + lhi * 8];
#pragma unroll
      for (int m = 0; m < 2; ++m)
#pragma unroll
        for (int n = 0; n < 4; ++n)
          acc1[m][n] = __builtin_amdgcn_mfma_f32_16x16x32_f16(a[m], b[n], acc1[m][n], 0, 0, 0);
    }
    __syncthreads();
  }

  // ---------------- phase 2a: sigmoid -> P (LDS, stride 257) ----------------
#pragma unroll
  for (int m = 0; m < 2; ++m)
#pragma unroll
    for (int n = 0; n < 4; ++n) {
      int col = wc * 64 + n * 16 + ln15;
#pragma unroll
      for (int j = 0; j < 4; ++j) {
        int rl = wr * 32 + m * 16 + lhi * 4 + j;
        float v = acc1[m][n][j] + bias_[n];
        sm.PC[rl * PSTR + col] = 1.f / (1.f + __expf(-v));
      }
    }
  __syncthreads();

  // ---------------- phase 2b: tree product -> muF (fragment layout) ----------------
  const int lf   = lane * 4;
  const int g_hi = lane >> 3;            // leaf>>5
  const int sub  = ((lane >> 1) & 3) * 16;
  const int j4   = (lane & 1) * 4;
#pragma unroll
  for (int rr = 0; rr < 8; ++rr) {
    int row = wave * 8 + rr;
    const float* p = &sm.PC[row * PSTR];
    float pre = 1.f;
#pragma unroll
    for (int d = 0; d < 6; ++d) {
      int node = (1 << d) - 1 + (lf >> (8 - d));
      int bit  = (lf >> (7 - d)) & 1;
      float g = p[node];
      pre *= bit ? g : (1.f - g);
    }
    float g6  = p[63 + lane];
    float g7a = p[127 + 2 * lane];
    float g7b = p[128 + 2 * lane];
    f16x4 o;
    o[0] = (_Float16)(pre * (1.f - g6) * (1.f - g7a));
    o[1] = (_Float16)(pre * (1.f - g6) * g7a);
    o[2] = (_Float16)(pre * g6 * (1.f - g7b));
    o[3] = (_Float16)(pre * g6 * g7b);
    *(f16x4*)&muF[(((row >> 4) * 8 + g_hi) * 64 + sub + (row & 15)) * 8 + j4] = o;
  }
  __syncthreads();

  // ---------------- phase 3: out = mu @ dist^T, staged row-streaming stores ----------------
  const int wr2 = wave >> 2, wc2 = wave & 3;   // rows wr2*32..+32, col strip wc2*32 per half
  // A fragments (shared across all col tiles): contiguous 16B/lane, conflict-free
  f16x8 aa0[8], aa1[8];
#pragma unroll
  for (int kk = 0; kk < 8; ++kk) {
    aa0[kk] = *(const f16x8*)&muF[(((wr2 * 2    ) * 8 + kk) * 64 + lane) * 8];
    aa1[kk] = *(const f16x8*)&muF[(((wr2 * 2 + 1) * 8 + kk) * 64 + lane) * 8];
  }

  for (int ctg = 0; ctg < 4; ++ctg) {          // 2 col-tiles (256 cols) per iteration
    f32x4 acc[2][2][2] = {};                   // [half][row-sub][col-sub]
#pragma unroll
    for (int h = 0; h < 2; ++h) {
      const int c16 = (ctg * 2 + h) * 8 + wc2 * 2;
      f16x8 bb0[8], bb1[8];
#pragma unroll
      for (int kk = 0; kk < 8; ++kk) {         // 64 lanes x 16B contiguous (1KB/instr)
        bb0[kk] = *(const f16x8*)&distF[(((size_t)(c16    ) * 8 + kk) * 64 + lane) * 8];
        bb1[kk] = *(const f16x8*)&distF[(((size_t)(c16 + 1) * 8 + kk) * 64 + lane) * 8];
      }
#pragma unroll
      for (int kk = 0; kk < 8; ++kk) {
        acc[h][0][0] = __builtin_amdgcn_mfma_f32_16x16x32_f16(aa0[kk], bb0[kk], acc[h][0][0], 0, 0, 0);
        acc[h][0][1] = __builtin_amdgcn_mfma_f32_16x16x32_f16(aa0[kk], bb1[kk], acc[h][0][1], 0, 0, 0);
        acc[h][1][0] = __builtin_amdgcn_mfma_f32_16x16x32_f16(aa1[kk], bb0[kk], acc[h][1][0], 0, 0, 0);
        acc[h][1][1] = __builtin_amdgcn_mfma_f32_16x16x32_f16(aa1[kk], bb1[kk], acc[h][1][1], 0, 0, 0);
      }
    }
    __syncthreads();                           // prev ctg's sC reads done
    // stage 64 x 256 f32 chunk
#pragma unroll
    for (int h = 0; h < 2; ++h)
#pragma unroll
      for (int rm = 0; rm < 2; ++rm)
#pragma unroll
        for (int cn = 0; cn < 2; ++cn) {
          int col = h * 128 + wc2 * 32 + cn * 16 + ln15;
#pragma unroll
          for (int j = 0; j < 4; ++j) {
            int rl = wr2 * 32 + rm * 16 + lhi * 4 + j;
            sm.PC[rl * CSTR + col] = acc[h][rm][cn][j];
          }
        }
    __syncthreads();
    // stream: each wave writes complete 1KB row-quarters (2 rows x 512B per instr)
    const int rsub = lane >> 5, q = lane & 31;
#pragma unroll
    for (int rr = 0; rr < 4; ++rr) {
      int row = wave * 8 + rr * 2 + rsub;
#pragma unroll
      for (int pass = 0; pass < 2; ++pass) {
        int q2 = pass * 32 + q;
        int col = ctg * 256 + q2 * 4;
        if (col < NCLS) {
          f32x4 v = *(const f32x4*)&sm.PC[row * CSTR + q2 * 4];
          *(f32x4*)&out[(size_t)(r0 + row) * NCLS + col] = v;
        }
      }
    }
  }
#undef P1_LOAD
#undef P1_WRITE
}

extern "C" void kernel_launch(void* const* d_in, const int* in_sizes, int n_in,
                              void* d_out, int out_size, void* d_ws, size_t ws_size,
                              hipStream_t stream) {
  const float* x  = (const float*)d_in[0];   // 16384x512
  const float* gw = (const float*)d_in[1];   // 255x512
  const float* gb = (const float*)d_in[2];   // 255
  const float* ll = (const float*)d_in[3];   // 256x1000
  float* out = (float*)d_out;                // 16384x1000
  char* ws = (char*)d_ws;

  _Float16* gwh   = (_Float16*)(ws);            // 262,144 B
  _Float16* distF = (_Float16*)(ws + 262144);   // 524,288 B (1024x256 swizzled)

  cvt_gw   <<<128, 256, 0, stream>>>((const float4*)gw, (f16x4*)gwh);
  softmax_t<<<256, 256, 0, stream>>>(ll, distF);
  fused    <<<BATCH / 64, 512, 0, stream>>>(x, gwh, gb, distF, out);
}

// Round 10
// 68.743 us; speedup vs baseline: 1.0259x; 1.0259x over previous
//
#include <hip/hip_runtime.h>

typedef __attribute__((ext_vector_type(8))) _Float16 f16x8;
typedef __attribute__((ext_vector_type(4))) _Float16 f16x4;
typedef __attribute__((ext_vector_type(4))) float   f32x4;

#define BATCH 16384
#define NFEAT 512
#define NCLS  1000
#define NLEAF 256
#define NINT  255
#define LDP   72    // staging LDS row stride (f16), 144B: 16B-aligned, 2-way banks
#define PSTR  257   // P LDS row stride (f32), odd: 2-way max on sigmoid writes

// ---- convert gate_w (255x512) -> f16 padded to 256x512 (row 255 = 0) ----
__global__ __launch_bounds__(256) void cvt_gw(const float4* __restrict__ in,
                                              f16x4* __restrict__ out) {
  int i = blockIdx.x * 256 + threadIdx.x;
  int row = i >> 7;
  f16x4 o;
  if (row < NINT) {
    float4 v = in[i];
    o[0] = (_Float16)v.x; o[1] = (_Float16)v.y;
    o[2] = (_Float16)v.z; o[3] = (_Float16)v.w;
  } else {
    o[0] = o[1] = o[2] = o[3] = (_Float16)0.f;
  }
  out[i] = o;
}

// ---- softmax of leaf_logits rows -> distF in MFMA-fragment-swizzled layout ----
// (class c, leaf l) at ((c>>4)*8 + (l>>5))*512 + ((l>>3&3)*16 + (c&15))*8 + (l&7)
__global__ __launch_bounds__(256) void softmax_t(const float* __restrict__ L,
                                                 _Float16* __restrict__ distF) {
  __shared__ float red[4];
  const int l = blockIdx.x, t = threadIdx.x;
  const int wave = t >> 6, lane = t & 63;
  const int kt = l >> 5, lhi_l = (l >> 3) & 3, jj = l & 7;
  float v[4];
  const bool live = t < 250;
  if (live) {
    float4 f = *(const float4*)&L[(size_t)l * NCLS + t * 4];
    v[0] = f.x; v[1] = f.y; v[2] = f.z; v[3] = f.w;
  } else {
    v[0] = v[1] = v[2] = v[3] = -1e30f;
  }
  float mx = fmaxf(fmaxf(v[0], v[1]), fmaxf(v[2], v[3]));
#pragma unroll
  for (int s = 32; s; s >>= 1) mx = fmaxf(mx, __shfl_xor(mx, s));
  if (lane == 0) red[wave] = mx;
  __syncthreads();
  mx = fmaxf(fmaxf(red[0], red[1]), fmaxf(red[2], red[3]));
  __syncthreads();
  float e[4], sum = 0.f;
#pragma unroll
  for (int i = 0; i < 4; ++i) { e[i] = __expf(v[i] - mx); sum += e[i]; }
  if (!live) { e[0] = e[1] = e[2] = e[3] = 0.f; sum = 0.f; }
#pragma unroll
  for (int s = 32; s; s >>= 1) sum += __shfl_xor(sum, s);
  if (lane == 0) red[wave] = sum;
  __syncthreads();
  sum = red[0] + red[1] + red[2] + red[3];
  float inv = 1.f / sum;
#pragma unroll
  for (int i = 0; i < 4; ++i) {
    int c = t * 4 + i;
    float val = live ? e[i] * inv : 0.f;
    int c16 = c >> 4, ln = c & 15;
    size_t idx = (((size_t)(c16 * 8 + kt)) * 64 + lhi_l * 16 + ln) * 8 + jj;
    distF[idx] = (_Float16)val;
  }
}

// ---- fused: gemm1 + sigmoid + tree + gemm2 ----
// BM=64, 256 blocks (1/CU), 512 threads (8 waves). min-waves=2 -> up to 256 VGPR, no spill.
__global__ __launch_bounds__(512, 2)
void fused(const float* __restrict__ x, const _Float16* __restrict__ gwh,
           const float* __restrict__ gb, const _Float16* __restrict__ distF,
           float* __restrict__ out) {
  __shared__ union {
    struct { _Float16 A[64 * LDP]; _Float16 B[256 * LDP]; } s;  // 46,080 B
    float P[64 * PSTR];                                         // 65,792 B
  } sm;
  __shared__ _Float16 muF[32 * 512];                            // 32,768 B, fragment layout

  const int tid  = threadIdx.x;
  const int wave = tid >> 6, lane = tid & 63;
  const int ln15 = lane & 15, lhi = lane >> 4;
  const int wr = wave >> 2, wc = wave & 3;      // phase1: 2x4 waves, 32r x 64c
  const int r0 = blockIdx.x * 64;

  float bias_[4];
#pragma unroll
  for (int n = 0; n < 4; ++n) {
    int col = wc * 64 + n * 16 + ln15;
    bias_[n] = (col < NINT) ? gb[col] : 0.f;
  }

  // ---------------- phase 1: logits = x @ gwh^T (2-deep reg prefetch) ----------------
  f32x4 acc1[2][4] = {};
  const int arow = tid >> 4, acol = (tid & 15) * 4;
  const int brow = tid >> 3, bcol = (tid & 7) * 8;

  float4 pa_[2], pa2_[2];
  uint4  pb_[2][4];

#define P1_LOAD(s, k0)                                                           \
  {                                                                              \
    pa_[s]  = *(const float4*)&x[(size_t)(r0 + arow) * NFEAT + (k0) + acol];     \
    pa2_[s] = *(const float4*)&x[(size_t)(r0 + 32 + arow) * NFEAT + (k0) + acol];\
    _Pragma("unroll")                                                            \
    for (int i = 0; i < 4; ++i)                                                  \
      pb_[s][i] = *(const uint4*)&gwh[(size_t)(i * 64 + brow) * NFEAT + (k0) + bcol];\
  }
#define P1_WRITE(s)                                                              \
  {                                                                              \
    f16x4 h;                                                                     \
    h[0] = (_Float16)pa_[s].x; h[1] = (_Float16)pa_[s].y;                        \
    h[2] = (_Float16)pa_[s].z; h[3] = (_Float16)pa_[s].w;                        \
    *(f16x4*)&sm.s.A[arow * LDP + acol] = h;                                     \
    h[0] = (_Float16)pa2_[s].x; h[1] = (_Float16)pa2_[s].y;                      \
    h[2] = (_Float16)pa2_[s].z; h[3] = (_Float16)pa2_[s].w;                      \
    *(f16x4*)&sm.s.A[(32 + arow) * LDP + acol] = h;                              \
    _Pragma("unroll")                                                            \
    for (int i = 0; i < 4; ++i)                                                  \
      *(uint4*)&sm.s.B[(i * 64 + brow) * LDP + bcol] = pb_[s][i];                \
  }

  P1_LOAD(0, 0);
  P1_LOAD(1, 64);
#pragma unroll
  for (int k = 0; k < NFEAT / 64; ++k) {
    const int s = k & 1;
    P1_WRITE(s);
    __syncthreads();
    if (k + 2 < NFEAT / 64) P1_LOAD(s, (k + 2) * 64);
#pragma unroll
    for (int kk = 0; kk < 2; ++kk) {
      f16x8 a[2], b[4];
#pragma unroll
      for (int m = 0; m < 2; ++m)
        a[m] = *(const f16x8*)&sm.s.A[(wr * 32 + m * 16 + ln15) * LDP + kk * 32 + lhi * 8];
#pragma unroll
      for (int n = 0; n < 4; ++n)
        b[n] = *(const f16x8*)&sm.s.B[(wc * 64 + n * 16 + ln15) * LDP + kk * 32 + lhi * 8];
#pragma unroll
      for (int m = 0; m < 2; ++m)
#pragma unroll
        for (int n = 0; n < 4; ++n)
          acc1[m][n] = __builtin_amdgcn_mfma_f32_16x16x32_f16(a[m], b[n], acc1[m][n], 0, 0, 0);
    }
    __syncthreads();
  }

  // ---------------- phase 2a: sigmoid -> P (LDS, stride 257) ----------------
#pragma unroll
  for (int m = 0; m < 2; ++m)
#pragma unroll
    for (int n = 0; n < 4; ++n) {
      int col = wc * 64 + n * 16 + ln15;
#pragma unroll
      for (int j = 0; j < 4; ++j) {
        int rl = wr * 32 + m * 16 + lhi * 4 + j;
        float v = acc1[m][n][j] + bias_[n];
        sm.P[rl * PSTR + col] = 1.f / (1.f + __expf(-v));
      }
    }
  __syncthreads();

  // ---------------- phase 2b: tree product -> muF (fragment layout) ----------------
  const int lf   = lane * 4;
  const int g_hi = lane >> 3;            // leaf>>5
  const int sub  = ((lane >> 1) & 3) * 16;
  const int j4   = (lane & 1) * 4;
#pragma unroll
  for (int rr = 0; rr < 8; ++rr) {
    int row = wave * 8 + rr;
    const float* p = &sm.P[row * PSTR];
    float pre = 1.f;
#pragma unroll
    for (int d = 0; d < 6; ++d) {
      int node = (1 << d) - 1 + (lf >> (8 - d));
      int bit  = (lf >> (7 - d)) & 1;
      float g = p[node];
      pre *= bit ? g : (1.f - g);
    }
    float g6  = p[63 + lane];
    float g7a = p[127 + 2 * lane];
    float g7b = p[128 + 2 * lane];
    f16x4 o;
    o[0] = (_Float16)(pre * (1.f - g6) * (1.f - g7a));
    o[1] = (_Float16)(pre * (1.f - g6) * g7a);
    o[2] = (_Float16)(pre * g6 * (1.f - g7b));
    o[3] = (_Float16)(pre * g6 * g7b);
    *(f16x4*)&muF[(((row >> 4) * 8 + g_hi) * 64 + sub + (row & 15)) * 8 + j4] = o;
  }
  __syncthreads();

  // ---------------- phase 3: out = mu @ dist^T, direct stores ----------------
  const int wr2 = wave >> 2, wc2 = wave & 3;   // rows wr2*32..+32, cols ct*128+wc2*32..+32
  f16x8 aa0[8], aa1[8];                        // A frags: contiguous, conflict-free
#pragma unroll
  for (int kk = 0; kk < 8; ++kk) {
    aa0[kk] = *(const f16x8*)&muF[(((wr2 * 2    ) * 8 + kk) * 64 + lane) * 8];
    aa1[kk] = *(const f16x8*)&muF[(((wr2 * 2 + 1) * 8 + kk) * 64 + lane) * 8];
  }

  for (int ct = 0; ct < 8; ++ct) {
    const int c16 = ct * 8 + wc2 * 2;
    f16x8 bb0[8], bb1[8];
#pragma unroll
    for (int kk = 0; kk < 8; ++kk) {           // 64 lanes x 16B = 1KB contiguous per load
      bb0[kk] = *(const f16x8*)&distF[(((size_t)(c16    ) * 8 + kk) * 64 + lane) * 8];
      bb1[kk] = *(const f16x8*)&distF[(((size_t)(c16 + 1) * 8 + kk) * 64 + lane) * 8];
    }
    f32x4 a00 = {}, a01 = {}, a10 = {}, a11 = {};
#pragma unroll
    for (int kk = 0; kk < 8; ++kk) {
      a00 = __builtin_amdgcn_mfma_f32_16x16x32_f16(aa0[kk], bb0[kk], a00, 0, 0, 0);
      a01 = __builtin_amdgcn_mfma_f32_16x16x32_f16(aa0[kk], bb1[kk], a01, 0, 0, 0);
      a10 = __builtin_amdgcn_mfma_f32_16x16x32_f16(aa1[kk], bb0[kk], a10, 0, 0, 0);
      a11 = __builtin_amdgcn_mfma_f32_16x16x32_f16(aa1[kk], bb1[kk], a11, 0, 0, 0);
    }
    int col0 = ct * 128 + wc2 * 32 + ln15;
    int col1 = col0 + 16;
    int rbase = r0 + wr2 * 32 + lhi * 4;
    if (col0 < NCLS) {
#pragma unroll
      for (int j = 0; j < 4; ++j) {
        out[(size_t)(rbase + j) * NCLS + col0]      = a00[j];
        out[(size_t)(rbase + 16 + j) * NCLS + col0] = a10[j];
      }
    }
    if (col1 < NCLS) {
#pragma unroll
      for (int j = 0; j < 4; ++j) {
        out[(size_t)(rbase + j) * NCLS + col1]      = a01[j];
        out[(size_t)(rbase + 16 + j) * NCLS + col1] = a11[j];
      }
    }
  }
#undef P1_LOAD
#undef P1_WRITE
}

extern "C" void kernel_launch(void* const* d_in, const int* in_sizes, int n_in,
                              void* d_out, int out_size, void* d_ws, size_t ws_size,
                              hipStream_t stream) {
  const float* x  = (const float*)d_in[0];   // 16384x512
  const float* gw = (const float*)d_in[1];   // 255x512
  const float* gb = (const float*)d_in[2];   // 255
  const float* ll = (const float*)d_in[3];   // 256x1000
  float* out = (float*)d_out;                // 16384x1000
  char* ws = (char*)d_ws;

  _Float16* gwh   = (_Float16*)(ws);            // 262,144 B
  _Float16* distF = (_Float16*)(ws + 262144);   // 524,288 B (1024x256 swizzled)

  cvt_gw   <<<128, 256, 0, stream>>>((const float4*)gw, (f16x4*)gwh);
  softmax_t<<<256, 256, 0, stream>>>(ll, distF);
  fused    <<<BATCH / 64, 512, 0, stream>>>(x, gwh, gb, distF, out);
}

// Round 11
// 65.479 us; speedup vs baseline: 1.0771x; 1.0498x over previous
//
#include <hip/hip_runtime.h>

typedef __attribute__((ext_vector_type(8))) _Float16 f16x8;
typedef __attribute__((ext_vector_type(4))) _Float16 f16x4;
typedef __attribute__((ext_vector_type(4))) float   f32x4;

#define BATCH 16384
#define NFEAT 512
#define NCLS  1000
#define NLEAF 256
#define NINT  255
#define LDP   72    // staging LDS row stride (f16), 144B: 16B-aligned, 2-way banks
#define PSTR  257   // P LDS row stride (f32), odd: 2-way max on sigmoid writes

// ---- convert gate_w (255x512) -> f16 padded to 256x512 (row 255 = 0) ----
__global__ __launch_bounds__(256) void cvt_gw(const float4* __restrict__ in,
                                              f16x4* __restrict__ out) {
  int i = blockIdx.x * 256 + threadIdx.x;
  int row = i >> 7;
  f16x4 o;
  if (row < NINT) {
    float4 v = in[i];
    o[0] = (_Float16)v.x; o[1] = (_Float16)v.y;
    o[2] = (_Float16)v.z; o[3] = (_Float16)v.w;
  } else {
    o[0] = o[1] = o[2] = o[3] = (_Float16)0.f;
  }
  out[i] = o;
}

// ---- softmax of leaf_logits rows -> distF in MFMA-fragment-swizzled layout ----
// (class c, leaf l) at ((c>>4)*8 + (l>>5))*512 + ((l>>3&3)*16 + (c&15))*8 + (l&7)
__global__ __launch_bounds__(256) void softmax_t(const float* __restrict__ L,
                                                 _Float16* __restrict__ distF) {
  __shared__ float red[4];
  const int l = blockIdx.x, t = threadIdx.x;
  const int wave = t >> 6, lane = t & 63;
  const int kt = l >> 5, lhi_l = (l >> 3) & 3, jj = l & 7;
  float v[4];
  const bool live = t < 250;
  if (live) {
    float4 f = *(const float4*)&L[(size_t)l * NCLS + t * 4];
    v[0] = f.x; v[1] = f.y; v[2] = f.z; v[3] = f.w;
  } else {
    v[0] = v[1] = v[2] = v[3] = -1e30f;
  }
  float mx = fmaxf(fmaxf(v[0], v[1]), fmaxf(v[2], v[3]));
#pragma unroll
  for (int s = 32; s; s >>= 1) mx = fmaxf(mx, __shfl_xor(mx, s));
  if (lane == 0) red[wave] = mx;
  __syncthreads();
  mx = fmaxf(fmaxf(red[0], red[1]), fmaxf(red[2], red[3]));
  __syncthreads();
  float e[4], sum = 0.f;
#pragma unroll
  for (int i = 0; i < 4; ++i) { e[i] = __expf(v[i] - mx); sum += e[i]; }
  if (!live) { e[0] = e[1] = e[2] = e[3] = 0.f; sum = 0.f; }
#pragma unroll
  for (int s = 32; s; s >>= 1) sum += __shfl_xor(sum, s);
  if (lane == 0) red[wave] = sum;
  __syncthreads();
  sum = red[0] + red[1] + red[2] + red[3];
  float inv = 1.f / sum;
#pragma unroll
  for (int i = 0; i < 4; ++i) {
    int c = t * 4 + i;
    float val = live ? e[i] * inv : 0.f;
    int c16 = c >> 4, ln = c & 15;
    size_t idx = (((size_t)(c16 * 8 + kt)) * 64 + lhi_l * 16 + ln) * 8 + jj;
    distF[idx] = (_Float16)val;
  }
}

// ---- fused: gemm1 + sigmoid + tree + gemm2 ----
// BM=64, 256 blocks (1/CU), 512 threads (8 waves).
// Phase-3 live set kept ~70 VGPR (bb[8]+acc0/1+transient aa) -> no spills.
__global__ __launch_bounds__(512, 2)
void fused(const float* __restrict__ x, const _Float16* __restrict__ gwh,
           const float* __restrict__ gb, const _Float16* __restrict__ distF,
           float* __restrict__ out) {
  __shared__ union {
    struct { _Float16 A[64 * LDP]; _Float16 B[256 * LDP]; } s;  // 46,080 B
    float P[64 * PSTR];                                         // 65,792 B
  } sm;
  __shared__ _Float16 muF[32 * 512];                            // 32,768 B, fragment layout

  const int tid  = threadIdx.x;
  const int wave = tid >> 6, lane = tid & 63;
  const int ln15 = lane & 15, lhi = lane >> 4;
  const int wr = wave >> 2, wc = wave & 3;      // phase1: 2x4 waves, 32r x 64c
  const int r0 = blockIdx.x * 64;

  float bias_[4];
#pragma unroll
  for (int n = 0; n < 4; ++n) {
    int col = wc * 64 + n * 16 + ln15;
    bias_[n] = (col < NINT) ? gb[col] : 0.f;
  }

  // ---------------- phase 1: logits = x @ gwh^T (2-deep reg prefetch) ----------------
  f32x4 acc1[2][4] = {};
  const int arow = tid >> 4, acol = (tid & 15) * 4;
  const int brow = tid >> 3, bcol = (tid & 7) * 8;

  float4 pa_[2], pa2_[2];
  uint4  pb_[2][4];

#define P1_LOAD(s, k0)                                                           \
  {                                                                              \
    pa_[s]  = *(const float4*)&x[(size_t)(r0 + arow) * NFEAT + (k0) + acol];     \
    pa2_[s] = *(const float4*)&x[(size_t)(r0 + 32 + arow) * NFEAT + (k0) + acol];\
    _Pragma("unroll")                                                            \
    for (int i = 0; i < 4; ++i)                                                  \
      pb_[s][i] = *(const uint4*)&gwh[(size_t)(i * 64 + brow) * NFEAT + (k0) + bcol];\
  }
#define P1_WRITE(s)                                                              \
  {                                                                              \
    f16x4 h;                                                                     \
    h[0] = (_Float16)pa_[s].x; h[1] = (_Float16)pa_[s].y;                        \
    h[2] = (_Float16)pa_[s].z; h[3] = (_Float16)pa_[s].w;                        \
    *(f16x4*)&sm.s.A[arow * LDP + acol] = h;                                     \
    h[0] = (_Float16)pa2_[s].x; h[1] = (_Float16)pa2_[s].y;                      \
    h[2] = (_Float16)pa2_[s].z; h[3] = (_Float16)pa2_[s].w;                      \
    *(f16x4*)&sm.s.A[(32 + arow) * LDP + acol] = h;                              \
    _Pragma("unroll")                                                            \
    for (int i = 0; i < 4; ++i)                                                  \
      *(uint4*)&sm.s.B[(i * 64 + brow) * LDP + bcol] = pb_[s][i];                \
  }

  P1_LOAD(0, 0);
  P1_LOAD(1, 64);
#pragma unroll
  for (int k = 0; k < NFEAT / 64; ++k) {
    const int s = k & 1;
    P1_WRITE(s);
    __syncthreads();
    if (k + 2 < NFEAT / 64) P1_LOAD(s, (k + 2) * 64);
#pragma unroll
    for (int kk = 0; kk < 2; ++kk) {
      f16x8 a[2], b[4];
#pragma unroll
      for (int m = 0; m < 2; ++m)
        a[m] = *(const f16x8*)&sm.s.A[(wr * 32 + m * 16 + ln15) * LDP + kk * 32 + lhi * 8];
#pragma unroll
      for (int n = 0; n < 4; ++n)
        b[n] = *(const f16x8*)&sm.s.B[(wc * 64 + n * 16 + ln15) * LDP + kk * 32 + lhi * 8];
#pragma unroll
      for (int m = 0; m < 2; ++m)
#pragma unroll
        for (int n = 0; n < 4; ++n)
          acc1[m][n] = __builtin_amdgcn_mfma_f32_16x16x32_f16(a[m], b[n], acc1[m][n], 0, 0, 0);
    }
    __syncthreads();
  }

  // ---------------- phase 2a: sigmoid -> P (LDS, stride 257) ----------------
#pragma unroll
  for (int m = 0; m < 2; ++m)
#pragma unroll
    for (int n = 0; n < 4; ++n) {
      int col = wc * 64 + n * 16 + ln15;
#pragma unroll
      for (int j = 0; j < 4; ++j) {
        int rl = wr * 32 + m * 16 + lhi * 4 + j;
        float v = acc1[m][n][j] + bias_[n];
        sm.P[rl * PSTR + col] = 1.f / (1.f + __expf(-v));
      }
    }
  __syncthreads();

  // ---------------- phase 2b: tree product -> muF (fragment layout) ----------------
  const int lf   = lane * 4;
  const int g_hi = lane >> 3;            // leaf>>5
  const int sub  = ((lane >> 1) & 3) * 16;
  const int j4   = (lane & 1) * 4;
#pragma unroll
  for (int rr = 0; rr < 8; ++rr) {
    int row = wave * 8 + rr;
    const float* p = &sm.P[row * PSTR];
    float pre = 1.f;
#pragma unroll
    for (int d = 0; d < 6; ++d) {
      int node = (1 << d) - 1 + (lf >> (8 - d));
      int bit  = (lf >> (7 - d)) & 1;
      float g = p[node];
      pre *= bit ? g : (1.f - g);
    }
    float g6  = p[63 + lane];
    float g7a = p[127 + 2 * lane];
    float g7b = p[128 + 2 * lane];
    f16x4 o;
    o[0] = (_Float16)(pre * (1.f - g6) * (1.f - g7a));
    o[1] = (_Float16)(pre * (1.f - g6) * g7a);
    o[2] = (_Float16)(pre * g6 * (1.f - g7b));
    o[3] = (_Float16)(pre * g6 * g7b);
    *(f16x4*)&muF[(((row >> 4) * 8 + g_hi) * 64 + sub + (row & 15)) * 8 + j4] = o;
  }
  __syncthreads();

  // ---------------- phase 3: out = mu @ dist^T, one 16-col group at a time ----------------
  // live set: bb[8]=32 + acc0/acc1=8 + transient a0/a1=8 VGPRs -> no spill.
  const int wr2 = wave >> 2, wc2 = wave & 3;
  const int rbase = r0 + wr2 * 32 + lhi * 4;
  for (int ct = 0; ct < 8; ++ct) {
#pragma unroll
    for (int h = 0; h < 2; ++h) {
      const int c16 = ct * 8 + wc2 * 2 + h;
      f16x8 bb[8];
#pragma unroll
      for (int kk = 0; kk < 8; ++kk)   // 64 lanes x 16B = 1KB contiguous per load
        bb[kk] = *(const f16x8*)&distF[(((size_t)c16 * 8 + kk) * 64 + lane) * 8];
      f32x4 acc0 = {}, acc1 = {};
#pragma unroll
      for (int kk = 0; kk < 8; ++kk) {
        f16x8 a0 = *(const f16x8*)&muF[(((wr2 * 2    ) * 8 + kk) * 64 + lane) * 8];
        f16x8 a1 = *(const f16x8*)&muF[(((wr2 * 2 + 1) * 8 + kk) * 64 + lane) * 8];
        acc0 = __builtin_amdgcn_mfma_f32_16x16x32_f16(a0, bb[kk], acc0, 0, 0, 0);
        acc1 = __builtin_amdgcn_mfma_f32_16x16x32_f16(a1, bb[kk], acc1, 0, 0, 0);
      }
      const int col = c16 * 16 + ln15;
      if (col < NCLS) {
#pragma unroll
        for (int j = 0; j < 4; ++j) {
          out[(size_t)(rbase + j) * NCLS + col]      = acc0[j];
          out[(size_t)(rbase + 16 + j) * NCLS + col] = acc1[j];
        }
      }
    }
  }
#undef P1_LOAD
#undef P1_WRITE
}

extern "C" void kernel_launch(void* const* d_in, const int* in_sizes, int n_in,
                              void* d_out, int out_size, void* d_ws, size_t ws_size,
                              hipStream_t stream) {
  const float* x  = (const float*)d_in[0];   // 16384x512
  const float* gw = (const float*)d_in[1];   // 255x512
  const float* gb = (const float*)d_in[2];   // 255
  const float* ll = (const float*)d_in[3];   // 256x1000
  float* out = (float*)d_out;                // 16384x1000
  char* ws = (char*)d_ws;

  _Float16* gwh   = (_Float16*)(ws);            // 262,144 B
  _Float16* distF = (_Float16*)(ws + 262144);   // 524,288 B (1024x256 swizzled)

  cvt_gw   <<<128, 256, 0, stream>>>((const float4*)gw, (f16x4*)gwh);
  softmax_t<<<256, 256, 0, stream>>>(ll, distF);
  fused    <<<BATCH / 64, 512, 0, stream>>>(x, gwh, gb, distF, out);
}